// Round 4
// baseline (397.401 us; speedup 1.0000x reference)
//
#include <hip/hip_runtime.h>
#include <stdint.h>

// ---------------------------------------------------------------------------
// Fused GQA MHA pipeline (MI355X):
//   1. prep: conv q,k,v fp32->bf16 AND transpose Wq,Wk,Wv (one launch).
//      WTk/WTv are stashed in d_out (scratch until gemmO writes it).
//   2. gemm_mid: Q-proj + K-proj + V-proj in ONE 768-block launch, ALL with
//      128x128 tiles, XCD-aware block swizzle; V-proj computed transposed.
//   3. attn(+TWo): flash attention (register-P, double-buffered async K/V
//      staging, 1 barrier/iter) with 64 extra blocks (blockIdx.y>=64)
//      transposing Wo -> WTo in the attn tail (WT is dead after gemm_mid).
//   4. output GEMM -> fp32 d_out (XCD swizzle).
// Launches: prep, gemm_mid, attn, gemmO  (4 total)
// ---------------------------------------------------------------------------

typedef __attribute__((ext_vector_type(8))) short short8;     // 8 bf16
typedef __attribute__((ext_vector_type(4))) float float4v;
typedef __attribute__((ext_vector_type(4))) unsigned short ushort4v;
typedef __attribute__((ext_vector_type(4))) unsigned int uint4v;

__device__ __forceinline__ unsigned short f2bf(float f) {
  union { float f; unsigned int u; } v; v.f = f;
  unsigned int r = v.u + 0x7fffu + ((v.u >> 16) & 1u);  // RNE
  return (unsigned short)(r >> 16);
}
__device__ __forceinline__ unsigned int fbits(float f) {
  union { float f; unsigned int u; } v; v.f = f; return v.u;
}
// pack two fp32 -> one dword of 2 bf16 (truncation), lo in bits[15:0]
__device__ __forceinline__ unsigned int pack_bf16_trunc(float lo, float hi) {
  return __builtin_amdgcn_perm(fbits(hi), fbits(lo), 0x07060302u);
}

__device__ __forceinline__ void gl2lds16(const unsigned short* g, unsigned short* l) {
  __builtin_amdgcn_global_load_lds(
      (const __attribute__((address_space(1))) void*)g,
      (__attribute__((address_space(3))) void*)l, 16, 0, 0);
}

// ---------------------------------------------------------------------------
// prep: grid (64,64,6), block (32,8).
//   z=0: transpose Wq [2048][2048] -> WTq
//   z=1: transpose Wk [2048][512]  -> WTk (in d_out scratch)
//   z=2: transpose Wv [2048][512]  -> WTv (in d_out scratch)
//   z=3..5: conv q/k/v fp32 -> bf16
// ---------------------------------------------------------------------------
__global__ void prep(const float* __restrict__ q, const float* __restrict__ k,
                     const float* __restrict__ v,
                     const float* __restrict__ Wq, const float* __restrict__ Wk,
                     const float* __restrict__ Wv,
                     unsigned short* __restrict__ qb, unsigned short* __restrict__ kb,
                     unsigned short* __restrict__ vb,
                     unsigned short* __restrict__ WTq, unsigned short* __restrict__ WTk,
                     unsigned short* __restrict__ WTv)
{
  __shared__ unsigned short t[32][33];
  const int z = blockIdx.z;
  if (z >= 3) {
    const float* in  = (z == 3) ? q : (z == 4) ? k : v;
    unsigned short* out = (z == 3) ? qb : (z == 4) ? kb : vb;
    const int tid = threadIdx.y * 32 + threadIdx.x;
    const int bid = blockIdx.y * 64 + blockIdx.x;
    for (int i = bid * 256 + tid; i < 2097152; i += 4096 * 256) {
      const float4v a = *(const float4v*)(in + (size_t)i * 4);
      *(ushort4v*)(out + (size_t)i * 4) = (ushort4v){f2bf(a.x), f2bf(a.y), f2bf(a.z), f2bf(a.w)};
    }
    return;
  }
  const float* in; unsigned short* out; int R, C;
  if (z == 0)      { in = Wq; out = WTq; R = 2048; C = 2048; }
  else if (z == 1) { in = Wk; out = WTk; R = 2048; C = 512; }
  else             { in = Wv; out = WTv; R = 2048; C = 512; }
  const int x0 = blockIdx.x * 32, y0 = blockIdx.y * 32;
  if (x0 >= C) return;
  const int tx = threadIdx.x, ty = threadIdx.y;   // 32 x 8
#pragma unroll
  for (int i = 0; i < 4; ++i) {
    const int r = y0 + ty + i * 8, c = x0 + tx;
    t[ty + i * 8][tx] = f2bf(in[(size_t)r * C + c]);
  }
  __syncthreads();
#pragma unroll
  for (int i = 0; i < 4; ++i)
    out[(size_t)(x0 + ty + i * 8) * R + y0 + tx] = t[tx][ty + i * 8];
}

// ---------------------------------------------------------------------------
// m97-style GEMM body: C[M,N] = (A[M,K] @ Bt[N,K]^T) * cscale, bf16 in,
// BK=32, 128xTN tile.
// ---------------------------------------------------------------------------
template<int TN, bool C_BF16>
__device__ void gemm_body(const unsigned short* __restrict__ A,
                          const unsigned short* __restrict__ Bt,
                          void* __restrict__ C, int N, int K, float cscale,
                          int bx, int by)
{
  constexpr int NT = TN / 32;
  constexpr int BI = TN / 64;
  __shared__ unsigned short As[128][32];
  __shared__ unsigned short Bs[TN][32];

  const int tid  = threadIdx.x;
  const int wave = tid >> 6;
  const int lane = tid & 63;
  const int quad = lane >> 4;
  const int l15  = lane & 15;
  const int wm   = (wave >> 1) * 64;
  const int wn   = (wave & 1) * (TN / 2);
  const int m0   = by * 128;
  const int n0   = bx * TN;

  const int srow = lane >> 2;
  const int skof = (lane & 3) * 8;

  float4v acc[4][NT];
#pragma unroll
  for (int i = 0; i < 4; ++i)
#pragma unroll
    for (int j = 0; j < NT; ++j) acc[i][j] = (float4v)0.0f;

  for (int k0 = 0; k0 < K; k0 += 32) {
    __syncthreads();
#pragma unroll
    for (int i = 0; i < 2; ++i) {
      const int row = wave * 32 + i * 16 + srow;
      gl2lds16(A + (size_t)(m0 + row) * K + k0 + skof, &As[wave * 32 + i * 16][0]);
    }
#pragma unroll
    for (int i = 0; i < BI; ++i) {
      const int row = wave * (TN / 4) + i * 16 + srow;
      gl2lds16(Bt + (size_t)(n0 + row) * K + k0 + skof, &Bs[wave * (TN / 4) + i * 16][0]);
    }
    __syncthreads();

    short8 af[4], bf[NT];
#pragma unroll
    for (int mt = 0; mt < 4; ++mt)  af[mt] = *(const short8*)&As[wm + mt * 16 + l15][quad * 8];
#pragma unroll
    for (int nt = 0; nt < NT; ++nt) bf[nt] = *(const short8*)&Bs[wn + nt * 16 + l15][quad * 8];
#pragma unroll
    for (int mt = 0; mt < 4; ++mt)
#pragma unroll
      for (int nt = 0; nt < NT; ++nt)
        acc[mt][nt] = __builtin_amdgcn_mfma_f32_16x16x32_bf16(af[mt], bf[nt], acc[mt][nt], 0, 0, 0);
  }

#pragma unroll
  for (int mt = 0; mt < 4; ++mt)
#pragma unroll
    for (int nt = 0; nt < NT; ++nt) {
      const int row = m0 + wm + mt * 16 + quad * 4;
      const int col = n0 + wn + nt * 16 + l15;
#pragma unroll
      for (int r = 0; r < 4; ++r) {
        const float val = acc[mt][nt][r] * cscale;
        if (C_BF16) ((unsigned short*)C)[(size_t)(row + r) * N + col] = f2bf(val);
        else        ((float*)C)[(size_t)(row + r) * N + col] = val;
      }
    }
}

// merged Q-proj + K-proj + V-proj, 768 blocks, all 128x128 tiles, per-segment
// XCD swizzle (all segment sizes divisible by 8 -> bijective):
//   id <  512: Qp[4096,2048] = qb @ WTq^T   (*SM_SCALE)
//   id <  640: Kp[4096,512]  = kb @ WTk^T
//   id >= 640: VpT[512,4096] = WTv @ vb^T   (C = V^T)
__global__ __launch_bounds__(256, 2)
void gemm_mid(const unsigned short* __restrict__ qb, const unsigned short* __restrict__ WTq,
              unsigned short* __restrict__ Qp,
              const unsigned short* __restrict__ kb, const unsigned short* __restrict__ WTk,
              unsigned short* __restrict__ Kp,
              const unsigned short* __restrict__ WTv, const unsigned short* __restrict__ vb,
              unsigned short* __restrict__ VpT, float sm_scale)
{
  const int id = blockIdx.x;
  if (id < 512) {
    const int s = (id & 7) * 64 + (id >> 3);
    gemm_body<128, true>(qb, WTq, Qp, 2048, 2048, sm_scale, s & 15, s >> 4);
  } else if (id < 640) {
    const int t = id - 512;
    const int s = (t & 7) * 16 + (t >> 3);
    gemm_body<128, true>(kb, WTk, Kp, 512, 2048, 1.0f, s & 3, s >> 2);
  } else {
    const int t = id - 640;
    const int s = (t & 7) * 16 + (t >> 3);
    gemm_body<128, true>(WTv, vb, VpT, 4096, 2048, 1.0f, s & 31, s >> 5);
  }
}

// 1D-grid XCD-swizzled GEMM (for the output projection)
template<int TN, bool C_BF16, int GX>
__global__ __launch_bounds__(256, 2)
void gemm_swz(const unsigned short* __restrict__ A, const unsigned short* __restrict__ Bt,
              void* __restrict__ C, int N, int K, float cscale)
{
  const int chunk = gridDim.x >> 3;
  const int s = (blockIdx.x & 7) * chunk + (blockIdx.x >> 3);
  gemm_body<TN, C_BF16>(A, Bt, C, N, K, cscale, s % GX, s / GX);
}

// ---------------------------------------------------------------------------
// Flash attention, double-buffered async staging, 1 barrier per key-tile.
// Qp [4096,2048] bf16 (pre-scaled by 1/8*log2e); Kp [4096,512]; VpT [512,4096];
// Ctx [4096,2048].  grid = (16 q-tiles of 128 rows, 64 heads + 4 transpose
// rows); wave = 32 q-rows.
//
// S computed transposed (A=K-frag, B=Q-frag -> same lane data).  K rows are
// staged in BIT-PERMUTED order (tile row position p holds global key
// k = {p4,p3,p2,p5,p1,p0}) so that each lane's S^T outputs are exactly the
// 16 logical keys its own PV A-fragment needs: P never touches LDS — two
// v_perm_b32 packs per (mt,nt) build the PV fragments in registers.
// V is still consumed in natural logical-key order -> V path unchanged.
// XOR chunk swizzle on staged tiles keeps unpadded ds_read_b128 conflict-free.
//
// blockIdx.y >= 64: transpose Wo (fp32) -> WTo bf16 (WT region is dead after
// gemm_mid consumed WTq; gemmO reads WTo next launch).
// ---------------------------------------------------------------------------
__global__ __launch_bounds__(256, 4)
void attn_flash(const unsigned short* __restrict__ Qp,
                const unsigned short* __restrict__ Kp,
                const unsigned short* __restrict__ VpT,
                unsigned short* __restrict__ Ctx,
                const float* __restrict__ Wo,
                unsigned short* __restrict__ WTo)
{
  __shared__ unsigned short Ks[2][64 * 64];
  __shared__ unsigned short VTs[2][64 * 64];

  const int tid  = threadIdx.x;

  if (blockIdx.y >= 64) {
    // ---- Wo transpose path: 64 blocks x 64 tiles of 32x32 ----
    unsigned short (*t)[33] = (unsigned short (*)[33])&Ks[0][0];
    const int bid = (blockIdx.y - 64) * 16 + blockIdx.x;   // 0..63
    const int tx = tid & 31, ty = tid >> 5;                // 32 x 8
    for (int tt = 0; tt < 64; ++tt) {
      const int tile = bid * 64 + tt;                      // 0..4095
      const int x0 = (tile & 63) * 32, y0 = (tile >> 6) * 32;
#pragma unroll
      for (int i = 0; i < 4; ++i)
        t[ty + i * 8][tx] = f2bf(Wo[(size_t)(y0 + ty + i * 8) * 2048 + x0 + tx]);
      __syncthreads();
#pragma unroll
      for (int i = 0; i < 4; ++i)
        WTo[(size_t)(x0 + ty + i * 8) * 2048 + y0 + tx] = t[tx][ty + i * 8];
      __syncthreads();
    }
    return;
  }

  const int wave = tid >> 6;
  const int lane = tid & 63;
  const int quad = lane >> 4;
  const int l15  = lane & 15;

  const int head = blockIdx.y;           // 0..63
  const int b    = head >> 5;
  const int hq   = head & 31;
  const int hkv  = hq >> 2;
  const size_t qrow = (size_t)(b * 2048 + blockIdx.x * 128 + wave * 32);

  short8 qf[2][2];
#pragma unroll
  for (int mt = 0; mt < 2; ++mt)
#pragma unroll
    for (int kc = 0; kc < 2; ++kc)
      qf[mt][kc] = *(const short8*)&Qp[(qrow + mt * 16 + l15) * 2048 + hq * 64 + kc * 32 + quad * 8];

  float4v oa[2][4];
  float4v lacc[2];
#pragma unroll
  for (int mt = 0; mt < 2; ++mt) {
    lacc[mt] = (float4v)0.0f;
#pragma unroll
    for (int dt = 0; dt < 4; ++dt) oa[mt][dt] = (float4v)0.0f;
  }
  short8 ones;
#pragma unroll
  for (int i = 0; i < 8; ++i) ones[i] = (short)0x3F80;   // bf16 1.0

  // async-stage key tile j into buffer `bu` (XOR chunk swizzle; K rows
  // bit-permuted: LDS row position p <- global key {p4,p3,p2,p5,p1,p0})
  auto stage = [&](int j, int bu) {
#pragma unroll
    for (int i = 0; i < 2; ++i) {
      const int s  = i * 256 + wave * 64 + lane;
      const int r  = s >> 3;
      const int lc = (s & 7) ^ (r & 7);
      const int rk = ((r >> 4) & 1) * 32 + ((r >> 2) & 3) * 8 + (r >> 5) * 4 + (r & 3);
      gl2lds16(Kp + (size_t)(b * 2048 + j * 64 + rk) * 512 + hkv * 64 + lc * 8,
               &Ks[bu][i * 2048 + wave * 512]);
      gl2lds16(VpT + (size_t)(hkv * 64 + r) * 4096 + b * 2048 + j * 64 + lc * 8,
               &VTs[bu][i * 2048 + wave * 512]);
    }
  };

  stage(0, 0);
  __syncthreads();

  for (int j = 0; j < 32; ++j) {
    const int bu = j & 1;
    if (j < 31) stage(j + 1, bu ^ 1);    // async; drained by loop-end barrier

    // ---- S^T = K Q^T (A=kf, B=qf: identical lane layouts) ----
    short8 kf[4][2];
#pragma unroll
    for (int nt = 0; nt < 4; ++nt) {
      const int krow = nt * 16 + l15;
      kf[nt][0] = *(const short8*)&Ks[bu][krow * 64 + ((quad ^ (l15 & 7)) * 8)];
      kf[nt][1] = *(const short8*)&Ks[bu][krow * 64 + (((4 + quad) ^ (l15 & 7)) * 8)];
    }

    __builtin_amdgcn_s_setprio(1);

    // After the key permutation, lane (quad,l15) at (mt,nt,r) holds logical
    // key (nt&1)*32 + quad*8 + (nt>>1)*4 + r at qrow l15 -> exactly PV A-frag
    // element order.  Pack exp2 results straight into bf16 dwords.
    unsigned int w[2][4][2];
#pragma unroll
    for (int mt = 0; mt < 2; ++mt) {
#pragma unroll
      for (int nt = 0; nt < 4; ++nt) {
        float4v sa = (float4v)0.0f;
        sa = __builtin_amdgcn_mfma_f32_16x16x32_bf16(kf[nt][0], qf[mt][0], sa, 0, 0, 0);
        sa = __builtin_amdgcn_mfma_f32_16x16x32_bf16(kf[nt][1], qf[mt][1], sa, 0, 0, 0);
        const float e0 = __builtin_amdgcn_exp2f(sa[0]);
        const float e1 = __builtin_amdgcn_exp2f(sa[1]);
        const float e2 = __builtin_amdgcn_exp2f(sa[2]);
        const float e3 = __builtin_amdgcn_exp2f(sa[3]);
        w[mt][nt][0] = pack_bf16_trunc(e0, e1);
        w[mt][nt][1] = pack_bf16_trunc(e2, e3);
      }
    }

    // ---- O += P V, l += P @ ones (P fragments built in registers) ----
#pragma unroll
    for (int kc = 0; kc < 2; ++kc) {
      union { uint4v u; short8 s; } p0u, p1u;
      p0u.u = (uint4v){w[0][kc][0], w[0][kc][1], w[0][kc + 2][0], w[0][kc + 2][1]};
      p1u.u = (uint4v){w[1][kc][0], w[1][kc][1], w[1][kc + 2][0], w[1][kc + 2][1]};
      const short8 pf0 = p0u.s;
      const short8 pf1 = p1u.s;
#pragma unroll
      for (int dt = 0; dt < 4; ++dt) {
        const int vrow = dt * 16 + l15;
        const short8 vf = *(const short8*)&VTs[bu][vrow * 64 + (((kc * 4 + quad) ^ (l15 & 7)) * 8)];
        oa[0][dt] = __builtin_amdgcn_mfma_f32_16x16x32_bf16(pf0, vf, oa[0][dt], 0, 0, 0);
        oa[1][dt] = __builtin_amdgcn_mfma_f32_16x16x32_bf16(pf1, vf, oa[1][dt], 0, 0, 0);
      }
      lacc[0] = __builtin_amdgcn_mfma_f32_16x16x32_bf16(pf0, ones, lacc[0], 0, 0, 0);
      lacc[1] = __builtin_amdgcn_mfma_f32_16x16x32_bf16(pf1, ones, lacc[1], 0, 0, 0);
    }

    __builtin_amdgcn_s_setprio(0);
    __syncthreads();   // compute done (buffer reuse safe) + drains stage(j+1)
  }

  // ---- epilogue: Ctx = O / l ----
#pragma unroll
  for (int mt = 0; mt < 2; ++mt)
#pragma unroll
    for (int r = 0; r < 4; ++r) {
      const float inv = 1.0f / lacc[mt][r];
#pragma unroll
      for (int dt = 0; dt < 4; ++dt)
        Ctx[(qrow + mt * 16 + quad * 4 + r) * 2048 + hq * 64 + dt * 16 + l15] =
            f2bf(oa[mt][dt][r] * inv);
    }
}

// ---------------------------------------------------------------------------
extern "C" void kernel_launch(void* const* d_in, const int* in_sizes, int n_in,
                              void* d_out, int out_size, void* d_ws, size_t ws_size,
                              hipStream_t stream)
{
  const float* q  = (const float*)d_in[0];
  const float* k  = (const float*)d_in[1];
  const float* v  = (const float*)d_in[2];
  const float* Wq = (const float*)d_in[3];
  const float* Wk = (const float*)d_in[4];
  const float* Wv = (const float*)d_in[5];
  const float* Wo = (const float*)d_in[6];
  float* out = (float*)d_out;

  unsigned short* ws  = (unsigned short*)d_ws;
  unsigned short* qb  = ws;                         // 4096x2048
  unsigned short* kb  = qb  + (size_t)8388608;      // 4096x2048
  unsigned short* vb  = kb  + (size_t)8388608;      // 4096x2048
  unsigned short* WT  = vb  + (size_t)8388608;      // 2048x2048 (WTq, later WTo)
  unsigned short* Qp  = WT  + (size_t)4194304;      // 4096x2048
  unsigned short* Kp  = Qp  + (size_t)8388608;      // 4096x512
  unsigned short* VpT = Kp  + (size_t)2097152;      // 512x4096
  unsigned short* Ctx = qb;                         // reuse qb after Q GEMM
  // WTk/WTv live in d_out (scratch until gemmO overwrites it at the end)
  unsigned short* WTk = (unsigned short*)d_out;               // 512x2048
  unsigned short* WTv = (unsigned short*)d_out + 1048576;     // 512x2048

  const dim3 blk(256);
  const dim3 tblk(32, 8);
  const float SM_SCALE = 0.125f * 1.44269504089f;   // 1/sqrt(64) * log2(e)

  // conv q/k/v + transpose Wq/Wk/Wv, one launch
  prep<<<dim3(64, 64, 6), tblk, 0, stream>>>(q, k, v, Wq, Wk, Wv,
                                             qb, kb, vb, WT, WTk, WTv);

  // Q-proj + K-proj + V-proj, one launch, all 128x128 tiles
  gemm_mid<<<dim3(768), blk, 0, stream>>>(qb, WT, Qp, kb, WTk, Kp, WTv, vb, VpT, SM_SCALE);

  // attention (writes Ctx = qb) + Wo transpose into WT (blocks y>=64)
  attn_flash<<<dim3(16, 68), blk, 0, stream>>>(Qp, Kp, VpT, Ctx, Wo, WT);

  // output projection -> fp32 d_out
  gemm_swz<128, false, 16><<<dim3(512), blk, 0, stream>>>(Ctx, WT, out, 2048, 2048, 1.0f);
}

// Round 7
// 351.274 us; speedup vs baseline: 1.1313x; 1.1313x over previous
//
#include <hip/hip_runtime.h>
#include <stdint.h>

// ---------------------------------------------------------------------------
// Fused GQA MHA pipeline (MI355X):
//   1. prep: conv q,k,v fp32->bf16 AND transpose Wq,Wk,Wv (one launch).
//      WTk/WTv are stashed in d_out (scratch until gemmO writes it).
//   2. gemm_mid: Q-proj + K-proj + V-proj in ONE 1024-block launch (2 full
//      occupancy waves at 2 blocks/CU), XCD-aware swizzle per segment;
//      V-proj computed transposed (C=V^T).
//   3. attn: flash attention (register-P, double-buffered async K/V staging,
//      1 barrier/iter); each block transposes 4 tiles of Wo -> WTo as tail
//      work (distributed, no straggler blocks).
//   4. output GEMM -> fp32 d_out (XCD swizzle).
// Launches: prep, gemm_mid, attn(+TWo tail), gemmO  (4 total)
// ---------------------------------------------------------------------------

typedef __attribute__((ext_vector_type(8))) short short8;     // 8 bf16
typedef __attribute__((ext_vector_type(4))) float float4v;
typedef __attribute__((ext_vector_type(4))) unsigned short ushort4v;
typedef __attribute__((ext_vector_type(4))) unsigned int uint4v;

__device__ __forceinline__ unsigned short f2bf(float f) {
  union { float f; unsigned int u; } v; v.f = f;
  unsigned int r = v.u + 0x7fffu + ((v.u >> 16) & 1u);  // RNE
  return (unsigned short)(r >> 16);
}
__device__ __forceinline__ unsigned int fbits(float f) {
  union { float f; unsigned int u; } v; v.f = f; return v.u;
}
// pack two fp32 -> one dword of 2 bf16 (truncation), lo in bits[15:0]
__device__ __forceinline__ unsigned int pack_bf16_trunc(float lo, float hi) {
  return __builtin_amdgcn_perm(fbits(hi), fbits(lo), 0x07060302u);
}

__device__ __forceinline__ void gl2lds16(const unsigned short* g, unsigned short* l) {
  __builtin_amdgcn_global_load_lds(
      (const __attribute__((address_space(1))) void*)g,
      (__attribute__((address_space(3))) void*)l, 16, 0, 0);
}

// ---------------------------------------------------------------------------
// prep: grid (64,64,6), block (32,8).
//   z=0: transpose Wq [2048][2048] -> WTq
//   z=1: transpose Wk [2048][512]  -> WTk (in d_out scratch)
//   z=2: transpose Wv [2048][512]  -> WTv (in d_out scratch)
//   z=3..5: conv q/k/v fp32 -> bf16
// ---------------------------------------------------------------------------
__global__ void prep(const float* __restrict__ q, const float* __restrict__ k,
                     const float* __restrict__ v,
                     const float* __restrict__ Wq, const float* __restrict__ Wk,
                     const float* __restrict__ Wv,
                     unsigned short* __restrict__ qb, unsigned short* __restrict__ kb,
                     unsigned short* __restrict__ vb,
                     unsigned short* __restrict__ WTq, unsigned short* __restrict__ WTk,
                     unsigned short* __restrict__ WTv)
{
  __shared__ unsigned short t[32][33];
  const int z = blockIdx.z;
  if (z >= 3) {
    const float* in  = (z == 3) ? q : (z == 4) ? k : v;
    unsigned short* out = (z == 3) ? qb : (z == 4) ? kb : vb;
    const int tid = threadIdx.y * 32 + threadIdx.x;
    const int bid = blockIdx.y * 64 + blockIdx.x;
    for (int i = bid * 256 + tid; i < 2097152; i += 4096 * 256) {
      const float4v a = *(const float4v*)(in + (size_t)i * 4);
      *(ushort4v*)(out + (size_t)i * 4) = (ushort4v){f2bf(a.x), f2bf(a.y), f2bf(a.z), f2bf(a.w)};
    }
    return;
  }
  const float* in; unsigned short* out; int R, C;
  if (z == 0)      { in = Wq; out = WTq; R = 2048; C = 2048; }
  else if (z == 1) { in = Wk; out = WTk; R = 2048; C = 512; }
  else             { in = Wv; out = WTv; R = 2048; C = 512; }
  const int x0 = blockIdx.x * 32, y0 = blockIdx.y * 32;
  if (x0 >= C) return;
  const int tx = threadIdx.x, ty = threadIdx.y;   // 32 x 8
#pragma unroll
  for (int i = 0; i < 4; ++i) {
    const int r = y0 + ty + i * 8, c = x0 + tx;
    t[ty + i * 8][tx] = f2bf(in[(size_t)r * C + c]);
  }
  __syncthreads();
#pragma unroll
  for (int i = 0; i < 4; ++i)
    out[(size_t)(x0 + ty + i * 8) * R + y0 + tx] = t[tx][ty + i * 8];
}

// ---------------------------------------------------------------------------
// m97-style GEMM body: C[M,N] = (A[M,K] @ Bt[N,K]^T) * cscale, bf16 in,
// BK=32, 128xTN tile.
// ---------------------------------------------------------------------------
template<int TN, bool C_BF16>
__device__ void gemm_body(const unsigned short* __restrict__ A,
                          const unsigned short* __restrict__ Bt,
                          void* __restrict__ C, int N, int K, float cscale,
                          int bx, int by)
{
  constexpr int NT = TN / 32;
  constexpr int BI = TN / 64;
  __shared__ unsigned short As[128][32];
  __shared__ unsigned short Bs[TN][32];

  const int tid  = threadIdx.x;
  const int wave = tid >> 6;
  const int lane = tid & 63;
  const int quad = lane >> 4;
  const int l15  = lane & 15;
  const int wm   = (wave >> 1) * 64;
  const int wn   = (wave & 1) * (TN / 2);
  const int m0   = by * 128;
  const int n0   = bx * TN;

  const int srow = lane >> 2;
  const int skof = (lane & 3) * 8;

  float4v acc[4][NT];
#pragma unroll
  for (int i = 0; i < 4; ++i)
#pragma unroll
    for (int j = 0; j < NT; ++j) acc[i][j] = (float4v)0.0f;

  for (int k0 = 0; k0 < K; k0 += 32) {
    __syncthreads();
#pragma unroll
    for (int i = 0; i < 2; ++i) {
      const int row = wave * 32 + i * 16 + srow;
      gl2lds16(A + (size_t)(m0 + row) * K + k0 + skof, &As[wave * 32 + i * 16][0]);
    }
#pragma unroll
    for (int i = 0; i < BI; ++i) {
      const int row = wave * (TN / 4) + i * 16 + srow;
      gl2lds16(Bt + (size_t)(n0 + row) * K + k0 + skof, &Bs[wave * (TN / 4) + i * 16][0]);
    }
    __syncthreads();

    short8 af[4], bf[NT];
#pragma unroll
    for (int mt = 0; mt < 4; ++mt)  af[mt] = *(const short8*)&As[wm + mt * 16 + l15][quad * 8];
#pragma unroll
    for (int nt = 0; nt < NT; ++nt) bf[nt] = *(const short8*)&Bs[wn + nt * 16 + l15][quad * 8];
#pragma unroll
    for (int mt = 0; mt < 4; ++mt)
#pragma unroll
      for (int nt = 0; nt < NT; ++nt)
        acc[mt][nt] = __builtin_amdgcn_mfma_f32_16x16x32_bf16(af[mt], bf[nt], acc[mt][nt], 0, 0, 0);
  }

#pragma unroll
  for (int mt = 0; mt < 4; ++mt)
#pragma unroll
    for (int nt = 0; nt < NT; ++nt) {
      const int row = m0 + wm + mt * 16 + quad * 4;
      const int col = n0 + wn + nt * 16 + l15;
#pragma unroll
      for (int r = 0; r < 4; ++r) {
        const float val = acc[mt][nt][r] * cscale;
        if (C_BF16) ((unsigned short*)C)[(size_t)(row + r) * N + col] = f2bf(val);
        else        ((float*)C)[(size_t)(row + r) * N + col] = val;
      }
    }
}

// merged Q-proj + K-proj + V-proj, 1024 blocks (= 2 full waves at 2/CU),
// XCD-swizzled per segment (all sub-ranges divisible by 8 -> bijective):
//   id <  512: Qp[4096,2048] = qb @ WTq^T   (*SM_SCALE)      TN=128
//   id <  768: Kp[4096,512]  = kb @ WTk^T                    TN=64
//   id >= 768: VpT[512,4096] = WTv @ vb^T   (C = V^T)        TN=64
__global__ __launch_bounds__(256, 2)
void gemm_mid(const unsigned short* __restrict__ qb, const unsigned short* __restrict__ WTq,
              unsigned short* __restrict__ Qp,
              const unsigned short* __restrict__ kb, const unsigned short* __restrict__ WTk,
              unsigned short* __restrict__ Kp,
              const unsigned short* __restrict__ WTv, const unsigned short* __restrict__ vb,
              unsigned short* __restrict__ VpT, float sm_scale)
{
  const int id = blockIdx.x;
  if (id < 512) {
    const int s = (id & 7) * 64 + (id >> 3);
    gemm_body<128, true>(qb, WTq, Qp, 2048, 2048, sm_scale, s & 15, s >> 4);
  } else if (id < 768) {
    const int t = id - 512;
    const int s = (t & 7) * 32 + (t >> 3);
    gemm_body<64, true>(kb, WTk, Kp, 512, 2048, 1.0f, s & 7, s >> 3);
  } else {
    const int t = id - 768;
    const int s = (t & 7) * 32 + (t >> 3);
    gemm_body<64, true>(WTv, vb, VpT, 4096, 2048, 1.0f, s & 63, s >> 6);
  }
}

// 1D-grid XCD-swizzled GEMM (for the output projection)
template<int TN, bool C_BF16, int GX>
__global__ __launch_bounds__(256, 2)
void gemm_swz(const unsigned short* __restrict__ A, const unsigned short* __restrict__ Bt,
              void* __restrict__ C, int N, int K, float cscale)
{
  const int chunk = gridDim.x >> 3;
  const int s = (blockIdx.x & 7) * chunk + (blockIdx.x >> 3);
  gemm_body<TN, C_BF16>(A, Bt, C, N, K, cscale, s % GX, s / GX);
}

// ---------------------------------------------------------------------------
// Flash attention, double-buffered async staging, 1 barrier per key-tile.
// Qp [4096,2048] bf16 (pre-scaled by 1/8*log2e); Kp [4096,512]; VpT [512,4096];
// Ctx [4096,2048].  grid = (16 q-tiles of 128 rows, 64 heads); wave = 32 rows.
//
// S computed transposed (A=K-frag, B=Q-frag -> same lane data).  K rows are
// staged in BIT-PERMUTED order (tile row position p holds global key
// k = {p4,p3,p2,p5,p1,p0}) so that each lane's S^T outputs are exactly the
// 16 logical keys its own PV A-fragment needs: P never touches LDS — two
// v_perm_b32 packs per (mt,nt) build the PV fragments in registers.
// V is still consumed in natural logical-key order -> V path unchanged.
// XOR chunk swizzle on staged tiles keeps unpadded ds_read_b128 conflict-free.
//
// Tail: each block transposes 4 tiles (32x32) of Wo -> WTo (WT region is
// dead after gemm_mid consumed WTq; gemmO reads WTo next launch).
// ---------------------------------------------------------------------------
__global__ __launch_bounds__(256, 4)
void attn_flash(const unsigned short* __restrict__ Qp,
                const unsigned short* __restrict__ Kp,
                const unsigned short* __restrict__ VpT,
                unsigned short* __restrict__ Ctx,
                const float* __restrict__ Wo,
                unsigned short* __restrict__ WTo)
{
  __shared__ unsigned short Ks[2][64 * 64];
  __shared__ unsigned short VTs[2][64 * 64];

  const int tid  = threadIdx.x;
  const int wave = tid >> 6;
  const int lane = tid & 63;
  const int quad = lane >> 4;
  const int l15  = lane & 15;

  const int head = blockIdx.y;           // 0..63
  const int b    = head >> 5;
  const int hq   = head & 31;
  const int hkv  = hq >> 2;
  const size_t qrow = (size_t)(b * 2048 + blockIdx.x * 128 + wave * 32);

  short8 qf[2][2];
#pragma unroll
  for (int mt = 0; mt < 2; ++mt)
#pragma unroll
    for (int kc = 0; kc < 2; ++kc)
      qf[mt][kc] = *(const short8*)&Qp[(qrow + mt * 16 + l15) * 2048 + hq * 64 + kc * 32 + quad * 8];

  float4v oa[2][4];
  float4v lacc[2];
#pragma unroll
  for (int mt = 0; mt < 2; ++mt) {
    lacc[mt] = (float4v)0.0f;
#pragma unroll
    for (int dt = 0; dt < 4; ++dt) oa[mt][dt] = (float4v)0.0f;
  }
  short8 ones;
#pragma unroll
  for (int i = 0; i < 8; ++i) ones[i] = (short)0x3F80;   // bf16 1.0

  // async-stage key tile j into buffer `bu` (XOR chunk swizzle; K rows
  // bit-permuted: LDS row position p <- global key {p4,p3,p2,p5,p1,p0})
  auto stage = [&](int j, int bu) {
#pragma unroll
    for (int i = 0; i < 2; ++i) {
      const int s  = i * 256 + wave * 64 + lane;
      const int r  = s >> 3;
      const int lc = (s & 7) ^ (r & 7);
      const int rk = ((r >> 4) & 1) * 32 + ((r >> 2) & 3) * 8 + (r >> 5) * 4 + (r & 3);
      gl2lds16(Kp + (size_t)(b * 2048 + j * 64 + rk) * 512 + hkv * 64 + lc * 8,
               &Ks[bu][i * 2048 + wave * 512]);
      gl2lds16(VpT + (size_t)(hkv * 64 + r) * 4096 + b * 2048 + j * 64 + lc * 8,
               &VTs[bu][i * 2048 + wave * 512]);
    }
  };

  stage(0, 0);
  __syncthreads();

  for (int j = 0; j < 32; ++j) {
    const int bu = j & 1;
    if (j < 31) stage(j + 1, bu ^ 1);    // async; drained by loop-end barrier

    // ---- S^T = K Q^T (A=kf, B=qf: identical lane layouts) ----
    short8 kf[4][2];
#pragma unroll
    for (int nt = 0; nt < 4; ++nt) {
      const int krow = nt * 16 + l15;
      kf[nt][0] = *(const short8*)&Ks[bu][krow * 64 + ((quad ^ (l15 & 7)) * 8)];
      kf[nt][1] = *(const short8*)&Ks[bu][krow * 64 + (((4 + quad) ^ (l15 & 7)) * 8)];
    }

    __builtin_amdgcn_s_setprio(1);

    // After the key permutation, lane (quad,l15) at (mt,nt,r) holds logical
    // key (nt&1)*32 + quad*8 + (nt>>1)*4 + r at qrow l15 -> exactly PV A-frag
    // element order.  Pack exp2 results straight into bf16 dwords.
    unsigned int w[2][4][2];
#pragma unroll
    for (int mt = 0; mt < 2; ++mt) {
#pragma unroll
      for (int nt = 0; nt < 4; ++nt) {
        float4v sa = (float4v)0.0f;
        sa = __builtin_amdgcn_mfma_f32_16x16x32_bf16(kf[nt][0], qf[mt][0], sa, 0, 0, 0);
        sa = __builtin_amdgcn_mfma_f32_16x16x32_bf16(kf[nt][1], qf[mt][1], sa, 0, 0, 0);
        const float e0 = __builtin_amdgcn_exp2f(sa[0]);
        const float e1 = __builtin_amdgcn_exp2f(sa[1]);
        const float e2 = __builtin_amdgcn_exp2f(sa[2]);
        const float e3 = __builtin_amdgcn_exp2f(sa[3]);
        w[mt][nt][0] = pack_bf16_trunc(e0, e1);
        w[mt][nt][1] = pack_bf16_trunc(e2, e3);
      }
    }

    // ---- O += P V, l += P @ ones (P fragments built in registers) ----
#pragma unroll
    for (int kc = 0; kc < 2; ++kc) {
      union { uint4v u; short8 s; } p0u, p1u;
      p0u.u = (uint4v){w[0][kc][0], w[0][kc][1], w[0][kc + 2][0], w[0][kc + 2][1]};
      p1u.u = (uint4v){w[1][kc][0], w[1][kc][1], w[1][kc + 2][0], w[1][kc + 2][1]};
      const short8 pf0 = p0u.s;
      const short8 pf1 = p1u.s;
#pragma unroll
      for (int dt = 0; dt < 4; ++dt) {
        const int vrow = dt * 16 + l15;
        const short8 vf = *(const short8*)&VTs[bu][vrow * 64 + (((kc * 4 + quad) ^ (l15 & 7)) * 8)];
        oa[0][dt] = __builtin_amdgcn_mfma_f32_16x16x32_bf16(pf0, vf, oa[0][dt], 0, 0, 0);
        oa[1][dt] = __builtin_amdgcn_mfma_f32_16x16x32_bf16(pf1, vf, oa[1][dt], 0, 0, 0);
      }
      lacc[0] = __builtin_amdgcn_mfma_f32_16x16x32_bf16(pf0, ones, lacc[0], 0, 0, 0);
      lacc[1] = __builtin_amdgcn_mfma_f32_16x16x32_bf16(pf1, ones, lacc[1], 0, 0, 0);
    }

    __builtin_amdgcn_s_setprio(0);
    __syncthreads();   // compute done (buffer reuse safe) + drains stage(j+1)
  }

  // ---- epilogue: Ctx = O / l ----
#pragma unroll
  for (int mt = 0; mt < 2; ++mt)
#pragma unroll
    for (int r = 0; r < 4; ++r) {
      const float inv = 1.0f / lacc[mt][r];
#pragma unroll
      for (int dt = 0; dt < 4; ++dt)
        Ctx[(qrow + mt * 16 + quad * 4 + r) * 2048 + hq * 64 + dt * 16 + l15] =
            f2bf(oa[mt][dt][r] * inv);
    }

  // ---- tail: transpose 4 tiles (32x32) of Wo -> WTo, distributed over all
  // 1024 blocks.  Ks reuse is safe: every wave passed the last loop barrier
  // and LDS is untouched since; waves write disjoint t rows, and a barrier
  // separates write from read.
  {
    unsigned short (*t)[33] = (unsigned short (*)[33])&Ks[0][0];
    const int bid = blockIdx.y * 16 + blockIdx.x;   // 0..1023
    const int tx = tid & 31, ty = tid >> 5;         // 32 x 8
#pragma unroll
    for (int tt = 0; tt < 4; ++tt) {
      const int tile = bid * 4 + tt;                // 0..4095
      const int x0 = (tile & 63) * 32, y0 = (tile >> 6) * 32;
#pragma unroll
      for (int i = 0; i < 4; ++i)
        t[ty + i * 8][tx] = f2bf(Wo[(size_t)(y0 + ty + i * 8) * 2048 + x0 + tx]);
      __syncthreads();
#pragma unroll
      for (int i = 0; i < 4; ++i)
        WTo[(size_t)(x0 + ty + i * 8) * 2048 + y0 + tx] = t[tx][ty + i * 8];
      __syncthreads();
    }
  }
}

// ---------------------------------------------------------------------------
extern "C" void kernel_launch(void* const* d_in, const int* in_sizes, int n_in,
                              void* d_out, int out_size, void* d_ws, size_t ws_size,
                              hipStream_t stream)
{
  const float* q  = (const float*)d_in[0];
  const float* k  = (const float*)d_in[1];
  const float* v  = (const float*)d_in[2];
  const float* Wq = (const float*)d_in[3];
  const float* Wk = (const float*)d_in[4];
  const float* Wv = (const float*)d_in[5];
  const float* Wo = (const float*)d_in[6];
  float* out = (float*)d_out;

  unsigned short* ws  = (unsigned short*)d_ws;
  unsigned short* qb  = ws;                         // 4096x2048
  unsigned short* kb  = qb  + (size_t)8388608;      // 4096x2048
  unsigned short* vb  = kb  + (size_t)8388608;      // 4096x2048
  unsigned short* WT  = vb  + (size_t)8388608;      // 2048x2048 (WTq, later WTo)
  unsigned short* Qp  = WT  + (size_t)4194304;      // 4096x2048
  unsigned short* Kp  = Qp  + (size_t)8388608;      // 4096x512
  unsigned short* VpT = Kp  + (size_t)2097152;      // 512x4096
  unsigned short* Ctx = qb;                         // reuse qb after Q GEMM
  // WTk/WTv live in d_out (scratch until gemmO overwrites it at the end)
  unsigned short* WTk = (unsigned short*)d_out;               // 512x2048
  unsigned short* WTv = (unsigned short*)d_out + 1048576;     // 512x2048

  const dim3 blk(256);
  const dim3 tblk(32, 8);
  const float SM_SCALE = 0.125f * 1.44269504089f;   // 1/sqrt(64) * log2(e)

  // conv q/k/v + transpose Wq/Wk/Wv, one launch
  prep<<<dim3(64, 64, 6), tblk, 0, stream>>>(q, k, v, Wq, Wk, Wv,
                                             qb, kb, vb, WT, WTk, WTv);

  // Q-proj + K-proj + V-proj, one launch (Q epilogue folds softmax scale)
  gemm_mid<<<dim3(1024), blk, 0, stream>>>(qb, WT, Qp, kb, WTk, Kp, WTv, vb, VpT, SM_SCALE);

  // attention (writes Ctx = qb) + distributed Wo transpose tail into WT
  attn_flash<<<dim3(16, 64), blk, 0, stream>>>(Qp, Kp, VpT, Ctx, Wo, WT);

  // output projection -> fp32 d_out
  gemm_swz<128, false, 16><<<dim3(512), blk, 0, stream>>>(Ctx, WT, out, 2048, 2048, 1.0f);
}

// Round 8
// 342.497 us; speedup vs baseline: 1.1603x; 1.0256x over previous
//
#include <hip/hip_runtime.h>
#include <stdint.h>

// ---------------------------------------------------------------------------
// Fused GQA MHA pipeline (MI355X):
//   1. prep: conv q,k,v fp32->bf16 AND transpose Wq,Wk,Wv (one launch).
//      WTk/WTv are stashed in d_out (scratch until gemmO writes it).
//   2. gemm_mid: Q-proj + K-proj + V-proj in ONE 1024-block launch,
//      XCD-aware swizzle per segment; V-proj computed transposed (C=V^T).
//      GEMM body: BK=64 (half the barrier drains of BK=32) with the
//      attn-verified XOR chunk swizzle on As/Bs -> conflict-free ds_read_b128.
//   3. attn: flash attention (register-P, double-buffered async K/V staging,
//      1 barrier/iter); each block transposes 4 tiles of Wo -> WTo as tail
//      work (distributed, no straggler blocks).
//   4. output GEMM -> fp32 d_out (XCD swizzle).
// Launches: prep, gemm_mid, attn(+TWo tail), gemmO  (4 total)
// ---------------------------------------------------------------------------

typedef __attribute__((ext_vector_type(8))) short short8;     // 8 bf16
typedef __attribute__((ext_vector_type(4))) float float4v;
typedef __attribute__((ext_vector_type(4))) unsigned short ushort4v;
typedef __attribute__((ext_vector_type(4))) unsigned int uint4v;

__device__ __forceinline__ unsigned short f2bf(float f) {
  union { float f; unsigned int u; } v; v.f = f;
  unsigned int r = v.u + 0x7fffu + ((v.u >> 16) & 1u);  // RNE
  return (unsigned short)(r >> 16);
}
__device__ __forceinline__ unsigned int fbits(float f) {
  union { float f; unsigned int u; } v; v.f = f; return v.u;
}
// pack two fp32 -> one dword of 2 bf16 (truncation), lo in bits[15:0]
__device__ __forceinline__ unsigned int pack_bf16_trunc(float lo, float hi) {
  return __builtin_amdgcn_perm(fbits(hi), fbits(lo), 0x07060302u);
}

__device__ __forceinline__ void gl2lds16(const unsigned short* g, unsigned short* l) {
  __builtin_amdgcn_global_load_lds(
      (const __attribute__((address_space(1))) void*)g,
      (__attribute__((address_space(3))) void*)l, 16, 0, 0);
}

// ---------------------------------------------------------------------------
// prep: grid (64,64,6), block (32,8).
//   z=0: transpose Wq [2048][2048] -> WTq
//   z=1: transpose Wk [2048][512]  -> WTk (in d_out scratch)
//   z=2: transpose Wv [2048][512]  -> WTv (in d_out scratch)
//   z=3..5: conv q/k/v fp32 -> bf16
// ---------------------------------------------------------------------------
__global__ void prep(const float* __restrict__ q, const float* __restrict__ k,
                     const float* __restrict__ v,
                     const float* __restrict__ Wq, const float* __restrict__ Wk,
                     const float* __restrict__ Wv,
                     unsigned short* __restrict__ qb, unsigned short* __restrict__ kb,
                     unsigned short* __restrict__ vb,
                     unsigned short* __restrict__ WTq, unsigned short* __restrict__ WTk,
                     unsigned short* __restrict__ WTv)
{
  __shared__ unsigned short t[32][33];
  const int z = blockIdx.z;
  if (z >= 3) {
    const float* in  = (z == 3) ? q : (z == 4) ? k : v;
    unsigned short* out = (z == 3) ? qb : (z == 4) ? kb : vb;
    const int tid = threadIdx.y * 32 + threadIdx.x;
    const int bid = blockIdx.y * 64 + blockIdx.x;
    for (int i = bid * 256 + tid; i < 2097152; i += 4096 * 256) {
      const float4v a = *(const float4v*)(in + (size_t)i * 4);
      *(ushort4v*)(out + (size_t)i * 4) = (ushort4v){f2bf(a.x), f2bf(a.y), f2bf(a.z), f2bf(a.w)};
    }
    return;
  }
  const float* in; unsigned short* out; int R, C;
  if (z == 0)      { in = Wq; out = WTq; R = 2048; C = 2048; }
  else if (z == 1) { in = Wk; out = WTk; R = 2048; C = 512; }
  else             { in = Wv; out = WTv; R = 2048; C = 512; }
  const int x0 = blockIdx.x * 32, y0 = blockIdx.y * 32;
  if (x0 >= C) return;
  const int tx = threadIdx.x, ty = threadIdx.y;   // 32 x 8
#pragma unroll
  for (int i = 0; i < 4; ++i) {
    const int r = y0 + ty + i * 8, c = x0 + tx;
    t[ty + i * 8][tx] = f2bf(in[(size_t)r * C + c]);
  }
  __syncthreads();
#pragma unroll
  for (int i = 0; i < 4; ++i)
    out[(size_t)(x0 + ty + i * 8) * R + y0 + tx] = t[tx][ty + i * 8];
}

// ---------------------------------------------------------------------------
// GEMM body: C[M,N] = (A[M,K] @ Bt[N,K]^T) * cscale, bf16 in, BK=64,
// 128xTN tile.  As/Bs rows are 64 shorts (128 B); the 8-short chunk index is
// XOR-swizzled with the row's low 3 bits (inverse swizzle applied on the
// GLOBAL source address, LDS dest linear — required by global_load_lds; the
// read applies the same XOR).  This is the attn-verified conflict-free
// pattern for ds_read_b128 at 128 B row stride.
// ---------------------------------------------------------------------------
template<int TN, bool C_BF16>
__device__ void gemm_body(const unsigned short* __restrict__ A,
                          const unsigned short* __restrict__ Bt,
                          void* __restrict__ C, int N, int K, float cscale,
                          int bx, int by)
{
  constexpr int NT = TN / 32;
  __shared__ unsigned short As[128][64];
  __shared__ unsigned short Bs[TN][64];

  const int tid  = threadIdx.x;
  const int wave = tid >> 6;
  const int lane = tid & 63;
  const int quad = lane >> 4;
  const int l15  = lane & 15;
  const int wm   = (wave >> 1) * 64;
  const int wn   = (wave & 1) * (TN / 2);
  const int m0   = by * 128;
  const int n0   = bx * TN;

  // staging decomposition: each gl2lds16 covers 8 rows x 64 cols (1 KB);
  // lane -> row offset r8 = lane>>3, source chunk lc = (lane&7) ^ r8.
  const int r8  = lane >> 3;
  const int lc8 = ((lane & 7) ^ r8) * 8;

  float4v acc[4][NT];
#pragma unroll
  for (int i = 0; i < 4; ++i)
#pragma unroll
    for (int j = 0; j < NT; ++j) acc[i][j] = (float4v)0.0f;

  for (int k0 = 0; k0 < K; k0 += 64) {
    __syncthreads();
#pragma unroll
    for (int i = 0; i < 4; ++i) {
      const int rb = i * 32 + wave * 8;
      gl2lds16(A + (size_t)(m0 + rb + r8) * K + k0 + lc8, &As[rb][0]);
    }
#pragma unroll
    for (int i = 0; i < TN / 32; ++i) {
      const int rb = i * 32 + wave * 8;
      gl2lds16(Bt + (size_t)(n0 + rb + r8) * K + k0 + lc8, &Bs[rb][0]);
    }
    __syncthreads();

#pragma unroll
    for (int kk = 0; kk < 2; ++kk) {
      const int cx = kk * 4 + quad;
      short8 af[4], bf[NT];
#pragma unroll
      for (int mt = 0; mt < 4; ++mt)
        af[mt] = *(const short8*)&As[wm + mt * 16 + l15][(cx ^ (l15 & 7)) * 8];
#pragma unroll
      for (int nt = 0; nt < NT; ++nt)
        bf[nt] = *(const short8*)&Bs[wn + nt * 16 + l15][(cx ^ (l15 & 7)) * 8];
#pragma unroll
      for (int mt = 0; mt < 4; ++mt)
#pragma unroll
        for (int nt = 0; nt < NT; ++nt)
          acc[mt][nt] = __builtin_amdgcn_mfma_f32_16x16x32_bf16(af[mt], bf[nt], acc[mt][nt], 0, 0, 0);
    }
  }

#pragma unroll
  for (int mt = 0; mt < 4; ++mt)
#pragma unroll
    for (int nt = 0; nt < NT; ++nt) {
      const int row = m0 + wm + mt * 16 + quad * 4;
      const int col = n0 + wn + nt * 16 + l15;
#pragma unroll
      for (int r = 0; r < 4; ++r) {
        const float val = acc[mt][nt][r] * cscale;
        if (C_BF16) ((unsigned short*)C)[(size_t)(row + r) * N + col] = f2bf(val);
        else        ((float*)C)[(size_t)(row + r) * N + col] = val;
      }
    }
}

// merged Q-proj + K-proj + V-proj, 1024 blocks (= 2 full waves at 2/CU),
// XCD-swizzled per segment (all sub-ranges divisible by 8 -> bijective):
//   id <  512: Qp[4096,2048] = qb @ WTq^T   (*SM_SCALE)      TN=128
//   id <  768: Kp[4096,512]  = kb @ WTk^T                    TN=64
//   id >= 768: VpT[512,4096] = WTv @ vb^T   (C = V^T)        TN=64
__global__ __launch_bounds__(256, 2)
void gemm_mid(const unsigned short* __restrict__ qb, const unsigned short* __restrict__ WTq,
              unsigned short* __restrict__ Qp,
              const unsigned short* __restrict__ kb, const unsigned short* __restrict__ WTk,
              unsigned short* __restrict__ Kp,
              const unsigned short* __restrict__ WTv, const unsigned short* __restrict__ vb,
              unsigned short* __restrict__ VpT, float sm_scale)
{
  const int id = blockIdx.x;
  if (id < 512) {
    const int s = (id & 7) * 64 + (id >> 3);
    gemm_body<128, true>(qb, WTq, Qp, 2048, 2048, sm_scale, s & 15, s >> 4);
  } else if (id < 768) {
    const int t = id - 512;
    const int s = (t & 7) * 32 + (t >> 3);
    gemm_body<64, true>(kb, WTk, Kp, 512, 2048, 1.0f, s & 7, s >> 3);
  } else {
    const int t = id - 768;
    const int s = (t & 7) * 32 + (t >> 3);
    gemm_body<64, true>(WTv, vb, VpT, 4096, 2048, 1.0f, s & 63, s >> 6);
  }
}

// 1D-grid XCD-swizzled GEMM (for the output projection)
template<int TN, bool C_BF16, int GX>
__global__ __launch_bounds__(256, 2)
void gemm_swz(const unsigned short* __restrict__ A, const unsigned short* __restrict__ Bt,
              void* __restrict__ C, int N, int K, float cscale)
{
  const int chunk = gridDim.x >> 3;
  const int s = (blockIdx.x & 7) * chunk + (blockIdx.x >> 3);
  gemm_body<TN, C_BF16>(A, Bt, C, N, K, cscale, s % GX, s / GX);
}

// ---------------------------------------------------------------------------
// Flash attention, double-buffered async staging, 1 barrier per key-tile.
// Qp [4096,2048] bf16 (pre-scaled by 1/8*log2e); Kp [4096,512]; VpT [512,4096];
// Ctx [4096,2048].  grid = (16 q-tiles of 128 rows, 64 heads); wave = 32 rows.
//
// S computed transposed (A=K-frag, B=Q-frag -> same lane data).  K rows are
// staged in BIT-PERMUTED order (tile row position p holds global key
// k = {p4,p3,p2,p5,p1,p0}) so that each lane's S^T outputs are exactly the
// 16 logical keys its own PV A-fragment needs: P never touches LDS — two
// v_perm_b32 packs per (mt,nt) build the PV fragments in registers.
// V is still consumed in natural logical-key order -> V path unchanged.
// XOR chunk swizzle on staged tiles keeps unpadded ds_read_b128 conflict-free.
//
// Tail: each block transposes 4 tiles (32x32) of Wo -> WTo (WT region is
// dead after gemm_mid consumed WTq; gemmO reads WTo next launch).
// ---------------------------------------------------------------------------
__global__ __launch_bounds__(256, 4)
void attn_flash(const unsigned short* __restrict__ Qp,
                const unsigned short* __restrict__ Kp,
                const unsigned short* __restrict__ VpT,
                unsigned short* __restrict__ Ctx,
                const float* __restrict__ Wo,
                unsigned short* __restrict__ WTo)
{
  __shared__ unsigned short Ks[2][64 * 64];
  __shared__ unsigned short VTs[2][64 * 64];

  const int tid  = threadIdx.x;
  const int wave = tid >> 6;
  const int lane = tid & 63;
  const int quad = lane >> 4;
  const int l15  = lane & 15;

  const int head = blockIdx.y;           // 0..63
  const int b    = head >> 5;
  const int hq   = head & 31;
  const int hkv  = hq >> 2;
  const size_t qrow = (size_t)(b * 2048 + blockIdx.x * 128 + wave * 32);

  short8 qf[2][2];
#pragma unroll
  for (int mt = 0; mt < 2; ++mt)
#pragma unroll
    for (int kc = 0; kc < 2; ++kc)
      qf[mt][kc] = *(const short8*)&Qp[(qrow + mt * 16 + l15) * 2048 + hq * 64 + kc * 32 + quad * 8];

  float4v oa[2][4];
  float4v lacc[2];
#pragma unroll
  for (int mt = 0; mt < 2; ++mt) {
    lacc[mt] = (float4v)0.0f;
#pragma unroll
    for (int dt = 0; dt < 4; ++dt) oa[mt][dt] = (float4v)0.0f;
  }
  short8 ones;
#pragma unroll
  for (int i = 0; i < 8; ++i) ones[i] = (short)0x3F80;   // bf16 1.0

  // async-stage key tile j into buffer `bu` (XOR chunk swizzle; K rows
  // bit-permuted: LDS row position p <- global key {p4,p3,p2,p5,p1,p0})
  auto stage = [&](int j, int bu) {
#pragma unroll
    for (int i = 0; i < 2; ++i) {
      const int s  = i * 256 + wave * 64 + lane;
      const int r  = s >> 3;
      const int lc = (s & 7) ^ (r & 7);
      const int rk = ((r >> 4) & 1) * 32 + ((r >> 2) & 3) * 8 + (r >> 5) * 4 + (r & 3);
      gl2lds16(Kp + (size_t)(b * 2048 + j * 64 + rk) * 512 + hkv * 64 + lc * 8,
               &Ks[bu][i * 2048 + wave * 512]);
      gl2lds16(VpT + (size_t)(hkv * 64 + r) * 4096 + b * 2048 + j * 64 + lc * 8,
               &VTs[bu][i * 2048 + wave * 512]);
    }
  };

  stage(0, 0);
  __syncthreads();

  for (int j = 0; j < 32; ++j) {
    const int bu = j & 1;
    if (j < 31) stage(j + 1, bu ^ 1);    // async; drained by loop-end barrier

    // ---- S^T = K Q^T (A=kf, B=qf: identical lane layouts) ----
    short8 kf[4][2];
#pragma unroll
    for (int nt = 0; nt < 4; ++nt) {
      const int krow = nt * 16 + l15;
      kf[nt][0] = *(const short8*)&Ks[bu][krow * 64 + ((quad ^ (l15 & 7)) * 8)];
      kf[nt][1] = *(const short8*)&Ks[bu][krow * 64 + (((4 + quad) ^ (l15 & 7)) * 8)];
    }

    __builtin_amdgcn_s_setprio(1);

    // After the key permutation, lane (quad,l15) at (mt,nt,r) holds logical
    // key (nt&1)*32 + quad*8 + (nt>>1)*4 + r at qrow l15 -> exactly PV A-frag
    // element order.  Pack exp2 results straight into bf16 dwords.
    unsigned int w[2][4][2];
#pragma unroll
    for (int mt = 0; mt < 2; ++mt) {
#pragma unroll
      for (int nt = 0; nt < 4; ++nt) {
        float4v sa = (float4v)0.0f;
        sa = __builtin_amdgcn_mfma_f32_16x16x32_bf16(kf[nt][0], qf[mt][0], sa, 0, 0, 0);
        sa = __builtin_amdgcn_mfma_f32_16x16x32_bf16(kf[nt][1], qf[mt][1], sa, 0, 0, 0);
        const float e0 = __builtin_amdgcn_exp2f(sa[0]);
        const float e1 = __builtin_amdgcn_exp2f(sa[1]);
        const float e2 = __builtin_amdgcn_exp2f(sa[2]);
        const float e3 = __builtin_amdgcn_exp2f(sa[3]);
        w[mt][nt][0] = pack_bf16_trunc(e0, e1);
        w[mt][nt][1] = pack_bf16_trunc(e2, e3);
      }
    }

    // ---- O += P V, l += P @ ones (P fragments built in registers) ----
#pragma unroll
    for (int kc = 0; kc < 2; ++kc) {
      union { uint4v u; short8 s; } p0u, p1u;
      p0u.u = (uint4v){w[0][kc][0], w[0][kc][1], w[0][kc + 2][0], w[0][kc + 2][1]};
      p1u.u = (uint4v){w[1][kc][0], w[1][kc][1], w[1][kc + 2][0], w[1][kc + 2][1]};
      const short8 pf0 = p0u.s;
      const short8 pf1 = p1u.s;
#pragma unroll
      for (int dt = 0; dt < 4; ++dt) {
        const int vrow = dt * 16 + l15;
        const short8 vf = *(const short8*)&VTs[bu][vrow * 64 + (((kc * 4 + quad) ^ (l15 & 7)) * 8)];
        oa[0][dt] = __builtin_amdgcn_mfma_f32_16x16x32_bf16(pf0, vf, oa[0][dt], 0, 0, 0);
        oa[1][dt] = __builtin_amdgcn_mfma_f32_16x16x32_bf16(pf1, vf, oa[1][dt], 0, 0, 0);
      }
      lacc[0] = __builtin_amdgcn_mfma_f32_16x16x32_bf16(pf0, ones, lacc[0], 0, 0, 0);
      lacc[1] = __builtin_amdgcn_mfma_f32_16x16x32_bf16(pf1, ones, lacc[1], 0, 0, 0);
    }

    __builtin_amdgcn_s_setprio(0);
    __syncthreads();   // compute done (buffer reuse safe) + drains stage(j+1)
  }

  // ---- epilogue: Ctx = O / l ----
#pragma unroll
  for (int mt = 0; mt < 2; ++mt)
#pragma unroll
    for (int r = 0; r < 4; ++r) {
      const float inv = 1.0f / lacc[mt][r];
#pragma unroll
      for (int dt = 0; dt < 4; ++dt)
        Ctx[(qrow + mt * 16 + quad * 4 + r) * 2048 + hq * 64 + dt * 16 + l15] =
            f2bf(oa[mt][dt][r] * inv);
    }

  // ---- tail: transpose 4 tiles (32x32) of Wo -> WTo, distributed over all
  // 1024 blocks.  Ks reuse is safe: every wave passed the last loop barrier
  // and LDS is untouched since; waves write disjoint t rows, and a barrier
  // separates write from read.
  {
    unsigned short (*t)[33] = (unsigned short (*)[33])&Ks[0][0];
    const int bid = blockIdx.y * 16 + blockIdx.x;   // 0..1023
    const int tx = tid & 31, ty = tid >> 5;         // 32 x 8
#pragma unroll
    for (int tt = 0; tt < 4; ++tt) {
      const int tile = bid * 4 + tt;                // 0..4095
      const int x0 = (tile & 63) * 32, y0 = (tile >> 6) * 32;
#pragma unroll
      for (int i = 0; i < 4; ++i)
        t[ty + i * 8][tx] = f2bf(Wo[(size_t)(y0 + ty + i * 8) * 2048 + x0 + tx]);
      __syncthreads();
#pragma unroll
      for (int i = 0; i < 4; ++i)
        WTo[(size_t)(x0 + ty + i * 8) * 2048 + y0 + tx] = t[tx][ty + i * 8];
      __syncthreads();
    }
  }
}

// ---------------------------------------------------------------------------
extern "C" void kernel_launch(void* const* d_in, const int* in_sizes, int n_in,
                              void* d_out, int out_size, void* d_ws, size_t ws_size,
                              hipStream_t stream)
{
  const float* q  = (const float*)d_in[0];
  const float* k  = (const float*)d_in[1];
  const float* v  = (const float*)d_in[2];
  const float* Wq = (const float*)d_in[3];
  const float* Wk = (const float*)d_in[4];
  const float* Wv = (const float*)d_in[5];
  const float* Wo = (const float*)d_in[6];
  float* out = (float*)d_out;

  unsigned short* ws  = (unsigned short*)d_ws;
  unsigned short* qb  = ws;                         // 4096x2048
  unsigned short* kb  = qb  + (size_t)8388608;      // 4096x2048
  unsigned short* vb  = kb  + (size_t)8388608;      // 4096x2048
  unsigned short* WT  = vb  + (size_t)8388608;      // 2048x2048 (WTq, later WTo)
  unsigned short* Qp  = WT  + (size_t)4194304;      // 4096x2048
  unsigned short* Kp  = Qp  + (size_t)8388608;      // 4096x512
  unsigned short* VpT = Kp  + (size_t)2097152;      // 512x4096
  unsigned short* Ctx = qb;                         // reuse qb after Q GEMM
  // WTk/WTv live in d_out (scratch until gemmO overwrites it at the end)
  unsigned short* WTk = (unsigned short*)d_out;               // 512x2048
  unsigned short* WTv = (unsigned short*)d_out + 1048576;     // 512x2048

  const dim3 blk(256);
  const dim3 tblk(32, 8);
  const float SM_SCALE = 0.125f * 1.44269504089f;   // 1/sqrt(64) * log2(e)

  // conv q/k/v + transpose Wq/Wk/Wv, one launch
  prep<<<dim3(64, 64, 6), tblk, 0, stream>>>(q, k, v, Wq, Wk, Wv,
                                             qb, kb, vb, WT, WTk, WTv);

  // Q-proj + K-proj + V-proj, one launch (Q epilogue folds softmax scale)
  gemm_mid<<<dim3(1024), blk, 0, stream>>>(qb, WT, Qp, kb, WTk, Kp, WTv, vb, VpT, SM_SCALE);

  // attention (writes Ctx = qb) + distributed Wo transpose tail into WT
  attn_flash<<<dim3(16, 64), blk, 0, stream>>>(Qp, Kp, VpT, Ctx, Wo, WT);

  // output projection -> fp32 d_out
  gemm_swz<128, false, 16><<<dim3(512), blk, 0, stream>>>(Ctx, WT, out, 2048, 2048, 1.0f);
}